// Round 7
// baseline (92.197 us; speedup 1.0000x reference)
//
#include <hip/hip_runtime.h>

#define BB 4
#define NN 4096
#define GC 16               // cells per axis
#define NC (GC * GC * GC)   // 4096 cells per batch
#define KS 9                // cell-split: each thread handles 3 of 27 neighbor cells

#if __has_builtin(__builtin_amdgcn_sqrtf)
  #define FAST_SQRT __builtin_amdgcn_sqrtf
#else
  #define FAST_SQRT sqrtf
#endif

__device__ __forceinline__ float clip1(float x) {
    return fminf(fmaxf(x, -1.0f), 1.0f);   // -> v_med3_f32
}

__device__ __forceinline__ int cell_of(float v) {
    int c = (int)floorf((v + 16.0f) * 0.5f);
    return min(GC - 1, max(0, c));
}

// ws layout (4-byte units):
#define CELLID_OFF 0                          // [BB][NN] int      16384
#define START_OFF  (CELLID_OFF + BB * NN)     // [BB][NC+1] int    16388
#define CURSOR_OFF (START_OFF + BB * (NC+1))  // [BB][NC] int      16384
#define SPTS_OFF   ((CURSOR_OFF + BB * NC + 3) & ~3)  // [BB][NN] float4 (16B aligned)
#define SIDX_OFF   (SPTS_OFF + BB * NN * 4)   // [BB][NN] int      16384
#define WS_FLOATS  (SIDX_OFF + BB * NN)

// Zero the cell counters and initialize out = coords (atomics add onto it).
__global__ __launch_bounds__(256) void k_init(
    const float* __restrict__ coords, float* __restrict__ out, int* __restrict__ cursor)
{
    const int t = blockIdx.x * 256 + threadIdx.x;
    if (t < BB * NN * 3) out[t] = coords[t];
    if (t < BB * NC) cursor[t] = 0;
}

// Per-point: compute cell id, store it, count.
__global__ __launch_bounds__(256) void k_count(
    const float* __restrict__ coords, int* __restrict__ cellid, int* __restrict__ cursor)
{
    const int t = blockIdx.x * 256 + threadIdx.x;
    if (t >= BB * NN) return;
    const int b = t / NN;
    const int cx = cell_of(coords[t * 3 + 0]);
    const int cy = cell_of(coords[t * 3 + 1]);
    const int cz = cell_of(coords[t * 3 + 2]);
    const int cid = (cz * GC + cy) * GC + cx;
    cellid[t] = cid;
    atomicAdd(&cursor[b * NC + cid], 1);
}

// One block per b: exclusive scan of 4096 counts (4 cells/thread), re-zero
// counters for the scatter pass, write start[] (incl. start[NC] = NN).
__global__ __launch_bounds__(1024) void k_scan(
    int* __restrict__ cursor, int* __restrict__ start)
{
    __shared__ int sl[1024];
    const int b = blockIdx.x;
    const int tid = threadIdx.x;
    const int c0 = tid * 4;
    int v0 = cursor[b * NC + c0 + 0];
    int v1 = cursor[b * NC + c0 + 1];
    int v2 = cursor[b * NC + c0 + 2];
    int v3 = cursor[b * NC + c0 + 3];
    cursor[b * NC + c0 + 0] = 0;
    cursor[b * NC + c0 + 1] = 0;
    cursor[b * NC + c0 + 2] = 0;
    cursor[b * NC + c0 + 3] = 0;
    const int mysum = v0 + v1 + v2 + v3;
    sl[tid] = mysum;
    __syncthreads();
    for (int off = 1; off < 1024; off <<= 1) {
        const int t = (tid >= off) ? sl[tid - off] : 0;
        __syncthreads();
        sl[tid] += t;
        __syncthreads();
    }
    int excl = sl[tid] - mysum;
    int* st = start + b * (NC + 1);
    st[c0 + 0] = excl; excl += v0;
    st[c0 + 1] = excl; excl += v1;
    st[c0 + 2] = excl; excl += v2;
    st[c0 + 3] = excl;
    if (tid == 1023) st[NC] = NN;
}

// Scatter points into cell-sorted order; remember original index.
__global__ __launch_bounds__(256) void k_scatter(
    const float* __restrict__ coords, const float* __restrict__ radii,
    const int* __restrict__ cellid, const int* __restrict__ start,
    int* __restrict__ cursor, float4* __restrict__ spts, int* __restrict__ sidx)
{
    const int t = blockIdx.x * 256 + threadIdx.x;
    if (t >= BB * NN) return;
    const int b = t / NN;
    const int cid = cellid[t];
    const int slot = start[b * (NC + 1) + cid] + atomicAdd(&cursor[b * NC + cid], 1);
    spts[b * NN + slot] = make_float4(coords[t * 3 + 0], coords[t * 3 + 1],
                                      coords[t * 3 + 2], radii[t]);
    sidx[b * NN + slot] = t - b * NN;
}

// Thread = (b, sorted point s, cell-subset k). Visits only the 27 neighbor
// cells; all skipped pairs have d >= 2 >= target -> exact zero contribution.
// Branchless inner (per-lane divergence; relu handles far pairs). Diagonal:
// p>0 but clip(0)=0 -> zero, matching reference. 3 float atomicAdds to out.
__global__ __launch_bounds__(256) void k_main(
    const float4* __restrict__ spts, const int* __restrict__ sidx,
    const int* __restrict__ start, float* __restrict__ out)
{
    const int b = blockIdx.z;
    const int kset = blockIdx.y;
    const int s = blockIdx.x * 256 + threadIdx.x;

    const float4 me = spts[b * NN + s];          // coalesced
    const float xi = me.x, yi = me.y, zi = me.z, ri = me.w;
    const int cx = cell_of(xi), cy = cell_of(yi), cz = cell_of(zi);
    const int* st = start + b * (NC + 1);
    const float4* sp = spts + b * NN;

    float ax = 0.0f, ay = 0.0f, az = 0.0f;

    #pragma unroll
    for (int mm = 0; mm < 3; ++mm) {
        const int m = kset * 3 + mm;             // 0..26
        const int nz = cz + m / 9 - 1;
        const int ny = cy + (m % 9) / 3 - 1;
        const int nx = cx + m % 3 - 1;
        if ((unsigned)nx < (unsigned)GC && (unsigned)ny < (unsigned)GC &&
            (unsigned)nz < (unsigned)GC) {
            const int cell = (nz * GC + ny) * GC + nx;
            const int jb = st[cell], je = st[cell + 1];
            for (int j = jb; j < je; ++j) {
                const float4 c = sp[j];
                const float dx = xi - c.x;
                const float dy = yi - c.y;
                const float dz = zi - c.z;
                const float d2 = fmaf(dx, dx, fmaf(dy, dy, dz * dz));
                const float dist = FAST_SQRT(d2);
                const float tgt = fmaxf(1.0f, ri + c.w);
                const float p = fmaxf(tgt - dist, 0.0f);
                ax = fmaf(p, clip1(dx), ax);
                ay = fmaf(p, clip1(dy), ay);
                az = fmaf(p, clip1(dz), az);
            }
        }
    }

    const int oi = sidx[b * NN + s];
    const int o = (b * NN + oi) * 3;
    const float sc = 0.1f / (float)NN;
    atomicAdd(&out[o + 0], sc * ax);
    atomicAdd(&out[o + 1], sc * ay);
    atomicAdd(&out[o + 2], sc * az);
}

// Fallback (ws too small): correctness backstop, brute force.
__global__ __launch_bounds__(256) void ncp_direct(
    const float* __restrict__ coords, const float* __restrict__ radii,
    float* __restrict__ out)
{
    __shared__ float4 jt[256];
    const int b = blockIdx.z;
    const int i = blockIdx.x * 256 + threadIdx.x;
    const float xi = coords[(b * NN + i) * 3 + 0];
    const float yi = coords[(b * NN + i) * 3 + 1];
    const float zi = coords[(b * NN + i) * 3 + 2];
    const float ri = radii[b * NN + i];
    float ax = 0.0f, ay = 0.0f, az = 0.0f;
    for (int jc = 0; jc < NN; jc += 256) {
        const int jj = jc + threadIdx.x;
        __syncthreads();
        jt[threadIdx.x] = make_float4(coords[(b * NN + jj) * 3 + 0],
                                      coords[(b * NN + jj) * 3 + 1],
                                      coords[(b * NN + jj) * 3 + 2],
                                      radii[b * NN + jj]);
        __syncthreads();
        #pragma unroll 4
        for (int k = 0; k < 256; ++k) {
            const float4 cc = jt[k];
            const float dx = xi - cc.x;
            const float dy = yi - cc.y;
            const float dz = zi - cc.z;
            const float d2 = fmaf(dx, dx, fmaf(dy, dy, dz * dz));
            if (__any(d2 < 4.0f)) {
                const float dist = FAST_SQRT(d2);
                const float tgt = fmaxf(1.0f, ri + cc.w);
                const float p = fmaxf(tgt - dist, 0.0f);
                ax = fmaf(p, clip1(dx), ax);
                ay = fmaf(p, clip1(dy), ay);
                az = fmaf(p, clip1(dz), az);
            }
        }
    }
    const int o = (b * NN + i) * 3;
    const float sc = 0.1f / (float)NN;
    out[o + 0] = fmaf(sc, ax, coords[o + 0]);
    out[o + 1] = fmaf(sc, ay, coords[o + 1]);
    out[o + 2] = fmaf(sc, az, coords[o + 2]);
}

extern "C" void kernel_launch(void* const* d_in, const int* in_sizes, int n_in,
                              void* d_out, int out_size, void* d_ws, size_t ws_size,
                              hipStream_t stream) {
    const float* coords = (const float*)d_in[0];
    const float* radii  = (const float*)d_in[1];
    float* out = (float*)d_out;

    if (ws_size >= (size_t)WS_FLOATS * sizeof(float)) {
        int* cellid   = (int*)d_ws + CELLID_OFF;
        int* start    = (int*)d_ws + START_OFF;
        int* cursor   = (int*)d_ws + CURSOR_OFF;
        float4* spts  = (float4*)((float*)d_ws + SPTS_OFF);
        int* sidx     = (int*)d_ws + SIDX_OFF;

        k_init<<<(BB * NN * 3 + 255) / 256, 256, 0, stream>>>(coords, out, cursor);
        k_count<<<(BB * NN + 255) / 256, 256, 0, stream>>>(coords, cellid, cursor);
        k_scan<<<BB, 1024, 0, stream>>>(cursor, start);
        k_scatter<<<(BB * NN + 255) / 256, 256, 0, stream>>>(
            coords, radii, cellid, start, cursor, spts, sidx);
        k_main<<<dim3(NN / 256, KS, BB), 256, 0, stream>>>(spts, sidx, start, out);
    } else {
        ncp_direct<<<dim3(NN / 256, 1, BB), 256, 0, stream>>>(coords, radii, out);
    }
}

// Round 8
// 73.710 us; speedup vs baseline: 1.2508x; 1.2508x over previous
//
#include <hip/hip_runtime.h>

#define BB 4
#define NN 4096
#define TPB 1024             // 16 waves
#define STREAMS 32           // j-streams per block = 16 waves x 2 half-waves
#define JPS (NN / STREAMS)   // 128 j's per stream
#define GRP 4                // LDS prefetch depth

#if __has_builtin(__builtin_amdgcn_sqrtf)
  #define FAST_SQRT __builtin_amdgcn_sqrtf
#else
  #define FAST_SQRT sqrtf
#endif

__device__ __forceinline__ float clip1(float x) {
    return fminf(fmaxf(x, -1.0f), 1.0f);   // -> v_med3_f32
}

// ONE kernel, no workspace. Block = (b, 32-i chunk). Phase 0: stage all 4096
// points of batch b into LDS as float4(x,y,z,r) (64 KB). Phase 1: lane ->
// (i = 32 per block, doubled across half-waves), each of 32 streams covers
// 128 consecutive j's from LDS (half-wave-uniform address = free 2-way).
// Early-out exact: radii in [0,1] -> target <= 2, so d2 >= 4 -> penalty 0.
// Diagonal: dx=0 exactly -> clip(0)=0 -> zero contribution (matches ref).
// Phase 2: LDS reuse for 32-stream reduction, epilogue writes out directly.
// 512 blocks = 2 blocks/CU (128 KB LDS <= 160 KB), 32 waves/CU.
__global__ __launch_bounds__(TPB, 8) void ncp_one(
    const float* __restrict__ coords,   // [BB,NN,3]
    const float* __restrict__ radii,    // [BB,NN]
    float* __restrict__ out)
{
    __shared__ __align__(16) char smem[65536];
    float4* pts = (float4*)smem;        // [NN] during phase 0/1
    float*  red = (float*)smem;         // [STREAMS*32*3] during phase 2

    const int b = blockIdx.z;
    const int ibase = blockIdx.x * 32;

    for (int p = threadIdx.x; p < NN; p += TPB) {
        const int g = b * NN + p;
        pts[p] = make_float4(coords[3 * g + 0], coords[3 * g + 1],
                             coords[3 * g + 2], radii[g]);
    }
    __syncthreads();

    const int l = threadIdx.x & 63;
    const int li = l & 31;              // i within chunk
    const int half = l >> 5;            // 0/1
    const int w = threadIdx.x >> 6;     // wave 0..15
    const int stream = w * 2 + half;    // 0..31
    const int i = ibase + li;

    const float4 me = pts[i];
    const float xi = me.x, yi = me.y, zi = me.z, ri = me.w;
    const int jbase = stream * JPS;

    float ax = 0.0f, ay = 0.0f, az = 0.0f;

    for (int k0 = 0; k0 < JPS; k0 += GRP) {
        float4 c[GRP];
        #pragma unroll
        for (int g = 0; g < GRP; ++g)
            c[g] = pts[jbase + k0 + g];     // half-wave-uniform LDS read
        #pragma unroll
        for (int g = 0; g < GRP; ++g) {
            const float dx = xi - c[g].x;
            const float dy = yi - c[g].y;
            const float dz = zi - c[g].z;
            const float d2 = fmaf(dx, dx, fmaf(dy, dy, dz * dz));
            if (__any(d2 < 4.0f)) {         // wave-uniform branch
                const float dist = FAST_SQRT(d2);
                const float tgt  = fmaxf(1.0f, ri + c[g].w);
                const float p    = fmaxf(tgt - dist, 0.0f);
                ax = fmaf(p, clip1(dx), ax);
                ay = fmaf(p, clip1(dy), ay);
                az = fmaf(p, clip1(dz), az);
            }
        }
    }

    __syncthreads();                    // everyone done reading pts
    const int rb = (stream * 32 + li) * 3;
    red[rb + 0] = ax;
    red[rb + 1] = ay;
    red[rb + 2] = az;
    __syncthreads();

    if (threadIdx.x < 96) {
        const int ii = threadIdx.x / 3;     // 0..31
        const int comp = threadIdx.x % 3;
        float acc = 0.0f;
        #pragma unroll
        for (int s = 0; s < STREAMS; ++s)   // ascending s == ascending j
            acc += red[(s * 32 + ii) * 3 + comp];
        const int o = (b * NN + ibase + ii) * 3 + comp;
        out[o] = fmaf(0.1f / (float)NN, acc, coords[o]);
    }
}

extern "C" void kernel_launch(void* const* d_in, const int* in_sizes, int n_in,
                              void* d_out, int out_size, void* d_ws, size_t ws_size,
                              hipStream_t stream) {
    const float* coords = (const float*)d_in[0];
    const float* radii  = (const float*)d_in[1];
    float* out = (float*)d_out;
    (void)d_ws; (void)ws_size;

    ncp_one<<<dim3(NN / 32, 1, BB), TPB, 0, stream>>>(coords, radii, out);
}